// Round 1
// baseline (6338.264 us; speedup 1.0000x reference)
//
#include <hip/hip_runtime.h>
#include <hip/hip_bf16.h>

// Problem constants
#define NS 2560      // B*N sentences
#define NT 70        // tokens per sentence
#define NH 200       // hidden
#define NI 60        // input dim (50 + 5 + 5)
#define NG 600       // 3*NH gates
#define NREL 100
#define NBAG 128
#define NPB 20       // sentences per bag

typedef float v2f __attribute__((ext_vector_type(2)));

__device__ __forceinline__ v2f fma2(v2f a, v2f b, v2f c) {
    return __builtin_elementwise_fma(a, b, c);
}
__device__ __forceinline__ float sigf(float x) { return 1.0f / (1.0f + __expf(-x)); }
__device__ __forceinline__ float tanh_fast(float x) {
    float e = __expf(2.0f * x);
    return 1.0f - 2.0f / (e + 1.0f);
}

// ---------------------------------------------------------------------------
// Pack weights: Wp[dir][kp][g][c] (kp = k/2, c = k&1), k in [0,260):
//   k<60 -> W_ih[g][k], else W_hh[g][k-60]. One dir = 130*600*2 = 156000 floats.
// GRU threads read v2f at (kp*600+g): adjacent lanes (adjacent g) -> coalesced.
// ---------------------------------------------------------------------------
__global__ void prep_w_kernel(const float* __restrict__ WihF, const float* __restrict__ WhhF,
                              const float* __restrict__ WihB, const float* __restrict__ WhhB,
                              float* __restrict__ Wp) {
    int idx = blockIdx.x * 256 + threadIdx.x;
    if (idx >= 2 * 156000) return;
    int dir = idx / 156000;
    int r = idx - dir * 156000;
    int c = r & 1;
    int g = (r >> 1) % 600;
    int kp = r / 1200;
    int k = 2 * kp + c;
    const float* Wih = dir ? WihB : WihF;
    const float* Whh = dir ? WhhB : WhhF;
    Wp[idx] = (k < 60) ? Wih[g * 60 + k] : Whh[g * 200 + (k - 60)];
}

// ---------------------------------------------------------------------------
// Gather x[t][s][d] = concat(word_emb, pos1_emb, pos2_emb), fp32, [70][2560][60]
// t-major so a GRU block's per-step stage (20 sentences) is 4.8KB contiguous.
// ---------------------------------------------------------------------------
__global__ void gather_kernel(const int* __restrict__ tok, const int* __restrict__ p1,
                              const int* __restrict__ p2, const float* __restrict__ emb,
                              const float* __restrict__ pemb, float* __restrict__ x) {
    int idx = blockIdx.x * 256 + threadIdx.x;
    if (idx >= NT * NS * NI) return;
    int d = idx % NI;
    int st = idx / NI;
    int s = st % NS;
    int t = st / NS;
    int o = s * NT + t;
    float v;
    if (d < 50)      v = emb[(long)tok[o] * 50 + d];
    else if (d < 55) v = pemb[p1[o] * 5 + (d - 50)];
    else             v = pemb[p2[o] * 5 + (d - 55)];
    x[idx] = v;
}

// ---------------------------------------------------------------------------
// Persistent GRU: 256 blocks (128 fwd + 128 bwd), each owns 20 sentences for
// all 70 steps. h double-buffered in LDS -> one barrier per step.
// Thread task (1000 active of 1024): jp in [0,100) handles j=jp and j=jp+100
// (all 3 gates each), mg in [0,10) handles sentences m0=2*mg..+1.
// All LDS activation reads are wave-uniform broadcasts (free).
// ---------------------------------------------------------------------------
__global__ __launch_bounds__(1024, 1)
void gru_kernel(const float* __restrict__ x, const float* __restrict__ Wp,
                const float* __restrict__ bihF, const float* __restrict__ bhhF,
                const float* __restrict__ bihB, const float* __restrict__ bhhB,
                __hip_bfloat16* __restrict__ hf, __hip_bfloat16* __restrict__ hb) {
    const int blk = blockIdx.x;
    const int dir = blk >> 7;           // 0 = forward, 1 = backward
    const int grp = blk & 127;
    const int s0 = grp * NPB;
    const int tid = threadIdx.x;

    __shared__ __align__(16) float sh_h[2][NPB][NH];
    __shared__ __align__(16) float sh_x[2][NPB][NI];

    const bool act = tid < 1000;
    const int jp = act ? (tid % 100) : 0;
    const int mg = act ? (tid / 100) : 0;
    const int m0 = mg * 2;

    const float* bih = dir ? bihB : bihF;
    const float* bhh = dir ? bhhB : bhhF;
    const v2f* wpd = (const v2f*)(Wp + dir * 156000);

    const float br0  = bih[jp]       + bhh[jp];
    const float bz0  = bih[200 + jp] + bhh[200 + jp];
    const float bnx0 = bih[400 + jp];
    const float bnh0 = bhh[400 + jp];
    const float br1  = bih[100 + jp] + bhh[100 + jp];
    const float bz1  = bih[300 + jp] + bhh[300 + jp];
    const float bnx1 = bih[500 + jp];
    const float bnh1 = bhh[500 + jp];

    __hip_bfloat16* hd = dir ? hb : hf;

    // h0 = 0; stage x for first step into buffer 0
    for (int i = tid; i < 2 * NPB * NH; i += 1024) (&sh_h[0][0][0])[i] = 0.0f;
    {
        int tt0 = dir ? (NT - 1) : 0;
        const float* xs = x + ((long)tt0 * NS + s0) * NI;
        for (int i = tid; i < NPB * NI; i += 1024) (&sh_x[0][0][0])[i] = xs[i];
    }
    __syncthreads();

    for (int t = 0; t < NT; t++) {
        const int cur = t & 1;
        const int nxt = cur ^ 1;
        const int tt = dir ? (NT - 1 - t) : t;

        v2f ar0[2], az0[2], anx0[2], anh0[2];
        v2f ar1[2], az1[2], anx1[2], anh1[2];
        const v2f vz = {0.0f, 0.0f};
        #pragma unroll
        for (int m = 0; m < 2; m++) {
            ar0[m] = az0[m] = anx0[m] = anh0[m] = vz;
            ar1[m] = az1[m] = anx1[m] = anh1[m] = vz;
        }

        if (act) {
            // part 1: input contribution, k = 0..59 (kp 0..29)
            #pragma unroll 3
            for (int k4 = 0; k4 < NI; k4 += 4) {
                const v2f* wk = wpd + (k4 >> 1) * 600 + jp;
                v2f wra = wk[0],    wrb = wk[600];
                v2f wza = wk[200],  wzb = wk[800];
                v2f wna = wk[400],  wnb = wk[1000];
                v2f wra1 = wk[100], wrb1 = wk[700];
                v2f wza1 = wk[300], wzb1 = wk[900];
                v2f wna1 = wk[500], wnb1 = wk[1100];
                #pragma unroll
                for (int m = 0; m < 2; m++) {
                    float4 a = *(const float4*)&sh_x[cur][m0 + m][k4];
                    v2f a0 = {a.x, a.y}, a1 = {a.z, a.w};
                    ar0[m]  = fma2(a1, wrb,  fma2(a0, wra,  ar0[m]));
                    az0[m]  = fma2(a1, wzb,  fma2(a0, wza,  az0[m]));
                    anx0[m] = fma2(a1, wnb,  fma2(a0, wna,  anx0[m]));
                    ar1[m]  = fma2(a1, wrb1, fma2(a0, wra1, ar1[m]));
                    az1[m]  = fma2(a1, wzb1, fma2(a0, wza1, az1[m]));
                    anx1[m] = fma2(a1, wnb1, fma2(a0, wna1, anx1[m]));
                }
            }
            // part 2: hidden contribution, k = 60..259 (kp 30..129)
            #pragma unroll 2
            for (int k4 = 0; k4 < NH; k4 += 4) {
                const v2f* wk = wpd + (30 + (k4 >> 1)) * 600 + jp;
                v2f wra = wk[0],    wrb = wk[600];
                v2f wza = wk[200],  wzb = wk[800];
                v2f wna = wk[400],  wnb = wk[1000];
                v2f wra1 = wk[100], wrb1 = wk[700];
                v2f wza1 = wk[300], wzb1 = wk[900];
                v2f wna1 = wk[500], wnb1 = wk[1100];
                #pragma unroll
                for (int m = 0; m < 2; m++) {
                    float4 a = *(const float4*)&sh_h[cur][m0 + m][k4];
                    v2f a0 = {a.x, a.y}, a1 = {a.z, a.w};
                    ar0[m]  = fma2(a1, wrb,  fma2(a0, wra,  ar0[m]));
                    az0[m]  = fma2(a1, wzb,  fma2(a0, wza,  az0[m]));
                    anh0[m] = fma2(a1, wnb,  fma2(a0, wna,  anh0[m]));
                    ar1[m]  = fma2(a1, wrb1, fma2(a0, wra1, ar1[m]));
                    az1[m]  = fma2(a1, wzb1, fma2(a0, wza1, az1[m]));
                    anh1[m] = fma2(a1, wnb1, fma2(a0, wna1, anh1[m]));
                }
            }

            // activations + h update (PyTorch GRU cell semantics)
            #pragma unroll
            for (int m = 0; m < 2; m++) {
                const int mm = m0 + m;
                const long gbase = ((long)(s0 + mm) * NT + tt) * NH;
                {
                    float r = sigf(ar0[m].x + ar0[m].y + br0);
                    float z = sigf(az0[m].x + az0[m].y + bz0);
                    float n = tanh_fast(anx0[m].x + anx0[m].y + bnx0 +
                                        r * (anh0[m].x + anh0[m].y + bnh0));
                    float hold = sh_h[cur][mm][jp];
                    float hn = (1.0f - z) * n + z * hold;
                    sh_h[nxt][mm][jp] = hn;
                    hd[gbase + jp] = __float2bfloat16(hn);
                }
                {
                    float r = sigf(ar1[m].x + ar1[m].y + br1);
                    float z = sigf(az1[m].x + az1[m].y + bz1);
                    float n = tanh_fast(anx1[m].x + anx1[m].y + bnx1 +
                                        r * (anh1[m].x + anh1[m].y + bnh1));
                    float hold = sh_h[cur][mm][100 + jp];
                    float hn = (1.0f - z) * n + z * hold;
                    sh_h[nxt][mm][100 + jp] = hn;
                    hd[gbase + 100 + jp] = __float2bfloat16(hn);
                }
            }
        }

        // stage x for next step into the other buffer (no race: readers use cur)
        if (t < NT - 1) {
            int ttn = dir ? (NT - 2 - t) : (t + 1);
            const float* xs = x + ((long)ttn * NS + s0) * NI;
            for (int i = tid; i < NPB * NI; i += 1024) (&sh_x[nxt][0][0])[i] = xs[i];
        }
        __syncthreads();
    }
}

// ---------------------------------------------------------------------------
// Word-level attention: one block per sentence. tup = hf+hb staged in LDS,
// scores = tanh(tup)@aw, softmax over T, H = alpha @ tup.
// ---------------------------------------------------------------------------
__global__ __launch_bounds__(256)
void attn_kernel(const __hip_bfloat16* __restrict__ hf, const __hip_bfloat16* __restrict__ hb,
                 const float* __restrict__ aw, float* __restrict__ H) {
    int s = blockIdx.x;
    int tid = threadIdx.x;
    __shared__ __align__(16) float tup[NT][NH];
    __shared__ float sc[NT];
    __shared__ float inv_s;
    const __hip_bfloat16* pf = hf + (long)s * NT * NH;
    const __hip_bfloat16* pb = hb + (long)s * NT * NH;
    for (int i = tid; i < NT * NH; i += 256)
        (&tup[0][0])[i] = __bfloat162float(pf[i]) + __bfloat162float(pb[i]);
    __syncthreads();
    int wv = tid >> 6, ln = tid & 63;
    for (int t = wv; t < NT; t += 4) {
        float p = 0.0f;
        for (int j = ln; j < NH; j += 64) p += tanh_fast(tup[t][j]) * aw[j];
        #pragma unroll
        for (int off = 32; off > 0; off >>= 1) p += __shfl_down(p, off, 64);
        if (ln == 0) sc[t] = p;
    }
    __syncthreads();
    if (tid == 0) {
        float mx = sc[0];
        for (int t = 1; t < NT; t++) mx = fmaxf(mx, sc[t]);
        float sum = 0.0f;
        for (int t = 0; t < NT; t++) { float e = __expf(sc[t] - mx); sc[t] = e; sum += e; }
        inv_s = 1.0f / sum;
    }
    __syncthreads();
    float inv = inv_s;
    for (int j = tid; j < NH; j += 256) {
        float acc = 0.0f;
        #pragma unroll 7
        for (int t = 0; t < NT; t++) acc += sc[t] * tup[t][j];
        H[s * NH + j] = acc * inv;
    }
}

// ---------------------------------------------------------------------------
// Bag attention + logits + BCE loss. One block per bag. Loss accumulated with
// atomicAdd into out[0] (zeroed via hipMemsetAsync before this kernel).
// ---------------------------------------------------------------------------
__global__ __launch_bounds__(256)
void bag_kernel(const float* __restrict__ H, const int* __restrict__ label,
                const float* __restrict__ sen_a, const float* __restrict__ sen_r,
                const float* __restrict__ rel, const float* __restrict__ sen_d,
                float* __restrict__ out) {
    int b = blockIdx.x;
    int tid = threadIdx.x;
    __shared__ __align__(16) float Hs[NPB][NH];
    __shared__ float e[NPB];
    __shared__ float Sv[NH];
    __shared__ float part[4];
    const float* Hb = H + b * NPB * NH;
    for (int i = tid; i < NPB * NH; i += 256) (&Hs[0][0])[i] = Hb[i];
    __syncthreads();
    int wv = tid >> 6, ln = tid & 63;
    for (int n = wv; n < NPB; n += 4) {
        float p = 0.0f;
        for (int j = ln; j < NH; j += 64) p += Hs[n][j] * sen_a[j] * sen_r[j];
        #pragma unroll
        for (int off = 32; off > 0; off >>= 1) p += __shfl_down(p, off, 64);
        if (ln == 0) e[n] = p;
    }
    __syncthreads();
    if (tid == 0) {
        float mx = e[0];
        for (int n = 1; n < NPB; n++) mx = fmaxf(mx, e[n]);
        float sum = 0.0f;
        for (int n = 0; n < NPB; n++) { float v = __expf(e[n] - mx); e[n] = v; sum += v; }
        float inv = 1.0f / sum;
        for (int n = 0; n < NPB; n++) e[n] *= inv;
    }
    __syncthreads();
    for (int j = tid; j < NH; j += 256) {
        float acc = 0.0f;
        #pragma unroll
        for (int n = 0; n < NPB; n++) acc += e[n] * Hs[n][j];
        Sv[j] = acc;
    }
    __syncthreads();
    float bce = 0.0f;
    if (tid < NREL) {
        float acc = 0.0f;
        #pragma unroll 4
        for (int j = 0; j < NH; j++) acc += Sv[j] * rel[tid * NH + j];
        float l = acc + sen_d[tid];
        out[1 + b * NREL + tid] = l;
        float tgt = (label[b] == tid) ? 1.0f : 0.0f;
        bce = fmaxf(l, 0.0f) - l * tgt + log1pf(__expf(-fabsf(l)));
    }
    #pragma unroll
    for (int off = 32; off > 0; off >>= 1) bce += __shfl_down(bce, off, 64);
    if (ln == 0) part[wv] = bce;
    __syncthreads();
    if (tid == 0) {
        float tot = (part[0] + part[1] + part[2] + part[3]) * (1.0f / NREL);
        atomicAdd(out, tot);
    }
}

// ---------------------------------------------------------------------------
extern "C" void kernel_launch(void* const* d_in, const int* in_sizes, int n_in,
                              void* d_out, int out_size, void* d_ws, size_t ws_size,
                              hipStream_t stream) {
    const int*   tok   = (const int*)d_in[0];
    const int*   p1    = (const int*)d_in[1];
    const int*   p2    = (const int*)d_in[2];
    const int*   label = (const int*)d_in[3];
    const float* emb   = (const float*)d_in[4];
    const float* pemb  = (const float*)d_in[5];
    const float* WihF  = (const float*)d_in[6];
    const float* WhhF  = (const float*)d_in[7];
    const float* bihF  = (const float*)d_in[8];
    const float* bhhF  = (const float*)d_in[9];
    const float* WihB  = (const float*)d_in[10];
    const float* WhhB  = (const float*)d_in[11];
    const float* bihB  = (const float*)d_in[12];
    const float* bhhB  = (const float*)d_in[13];
    const float* aw    = (const float*)d_in[14];
    const float* sen_a = (const float*)d_in[15];
    const float* sen_r = (const float*)d_in[16];
    const float* rel   = (const float*)d_in[17];
    const float* sen_d = (const float*)d_in[18];

    // workspace layout (floats / bf16), total ~190 MB
    float* wsf  = (float*)d_ws;
    float* Wp   = wsf;                         // 312000 f
    float* xbuf = Wp + 2 * 156000;             // 10,752,000 f
    float* Hbuf = xbuf + (long)NT * NS * NI;   // 512,000 f
    __hip_bfloat16* hfb = (__hip_bfloat16*)(Hbuf + NS * NH);   // 35,840,000 bf16
    __hip_bfloat16* hbb = hfb + (long)NS * NT * NH;            // 35,840,000 bf16

    prep_w_kernel<<<(2 * 156000 + 255) / 256, 256, 0, stream>>>(WihF, WhhF, WihB, WhhB, Wp);
    gather_kernel<<<(NT * NS * NI + 255) / 256, 256, 0, stream>>>(tok, p1, p2, emb, pemb, xbuf);
    gru_kernel<<<256, 1024, 0, stream>>>(xbuf, Wp, bihF, bhhF, bihB, bhhB, hfb, hbb);
    attn_kernel<<<NS, 256, 0, stream>>>(hfb, hbb, aw, Hbuf);
    hipMemsetAsync(d_out, 0, sizeof(float), stream);
    bag_kernel<<<NBAG, 256, 0, stream>>>(Hbuf, label, sen_a, sen_r, rel, sen_d, (float*)d_out);
}

// Round 2
// 1214.693 us; speedup vs baseline: 5.2180x; 5.2180x over previous
//
#include <hip/hip_runtime.h>
#include <hip/hip_bf16.h>

// Problem constants
#define NS 2560      // B*N sentences
#define NT 70        // tokens per sentence
#define NH 200       // hidden
#define NI 60        // input dim (50 + 5 + 5)
#define NREL 100
#define NBAG 128
#define NPB 20       // sentences per bag

#define NTRI 14      // gate triples (each 16 gates; 200 -> 224 padded per segment)
#define KT_TOT 9     // K tiles of 32: 2 for x (60->64), 7 for h (200->224)
#define FRAG 512     // elements per B fragment (64 lanes x 8)

typedef unsigned short ushort_t;
typedef __attribute__((ext_vector_type(8))) short bf16x8;
typedef __attribute__((ext_vector_type(4))) float f32x4;

__device__ __forceinline__ float sigf(float x) { return 1.0f / (1.0f + __expf(-x)); }
__device__ __forceinline__ float tanh_fast(float x) {
    float e = __expf(2.0f * x);
    return 1.0f - 2.0f / (e + 1.0f);
}
__device__ __forceinline__ ushort_t f2b(float f) {
    __hip_bfloat16 h = __float2bfloat16(f);
    return *(ushort_t*)&h;
}

// ---------------------------------------------------------------------------
// Pack weights into MFMA B-fragment order, bf16, zero-padded:
//   Wpk[dir][triple i (14)][seg (3: r,z,n)][ktile (9)][lane (64)][j (8)]
// B-fragment element for 16x16x32: lane ln holds B[k=(ln>>4)*8+j][n=ln&15],
// with n -> gate g = seg*200 + 16*i + (ln&15), k -> kt<2: x-dim, kt>=2: h-dim.
// ---------------------------------------------------------------------------
__global__ void prep_wpk_kernel(const float* __restrict__ WihF, const float* __restrict__ WhhF,
                                const float* __restrict__ WihB, const float* __restrict__ WhhB,
                                ushort_t* __restrict__ Wpk) {
    int idx = blockIdx.x * 256 + threadIdx.x;
    const int total = 2 * NTRI * 3 * KT_TOT * FRAG;
    if (idx >= total) return;
    int e = idx & 511;
    int f = idx >> 9;
    int j = e & 7;
    int ln = e >> 3;
    int kt = f % KT_TOT;
    int t3 = f / KT_TOT;
    int seg = t3 % 3;
    int t14 = t3 / 3;
    int i = t14 % NTRI;
    int d = t14 / NTRI;
    const float* Wih = d ? WihB : WihF;
    const float* Whh = d ? WhhB : WhhF;
    int gl = 16 * i + (ln & 15);
    int kk = ((ln >> 4) << 3) + j;
    float v = 0.0f;
    if (gl < NH) {
        int g = seg * NH + gl;
        if (kt < 2) {
            int kx = kt * 32 + kk;
            if (kx < NI) v = Wih[g * NI + kx];
        } else {
            int kh = (kt - 2) * 32 + kk;
            if (kh < NH) v = Whh[g * NH + kh];
        }
    }
    Wpk[idx] = f2b(v);
}

// ---------------------------------------------------------------------------
// Gather x[t][s][d] = concat(word_emb, pos1_emb, pos2_emb), fp32, [70][2560][60]
// ---------------------------------------------------------------------------
__global__ void gather_kernel(const int* __restrict__ tok, const int* __restrict__ p1,
                              const int* __restrict__ p2, const float* __restrict__ emb,
                              const float* __restrict__ pemb, float* __restrict__ x) {
    int idx = blockIdx.x * 256 + threadIdx.x;
    if (idx >= NT * NS * NI) return;
    int d = idx % NI;
    int st = idx / NI;
    int s = st % NS;
    int t = st / NS;
    int o = s * NT + t;
    float v;
    if (d < 50)      v = emb[(long)tok[o] * 50 + d];
    else if (d < 55) v = pemb[p1[o] * 5 + (d - 50)];
    else             v = pemb[p2[o] * 5 + (d - 55)];
    x[idx] = v;
}

// ---------------------------------------------------------------------------
// MFMA GRU. 256 blocks (128 groups x 2 dirs), 448 threads = 7 waves.
// Wave w owns triples {w, w+7}; triple i = gates j in [16i,16i+16) for r,z,n.
// Per step: acc[m-tile 0..1] = A(20x288, LDS bf16, A-frag layout) x
//                              B(288x16 per seg, global fragment stream).
// h-update lane-local (C-layout col==B n-col), h_old in registers.
// One barrier per step; A double-buffered.
// ---------------------------------------------------------------------------
__global__ __launch_bounds__(448, 1)
void gru_kernel(const float* __restrict__ x, const ushort_t* __restrict__ Wpk,
                const float* __restrict__ bihF, const float* __restrict__ bhhF,
                const float* __restrict__ bihB, const float* __restrict__ bhhB,
                __hip_bfloat16* __restrict__ hfo, __hip_bfloat16* __restrict__ hbo) {
    const int dir = blockIdx.x >> 7;
    const int s0 = (blockIdx.x & 127) * NPB;
    const int tid = threadIdx.x;
    const int wv = tid >> 6, ln = tid & 63;
    const int c = ln & 15, quad = ln >> 4;

    // A-operand buffers in A-fragment-friendly layout, row stride 40 ushorts
    // (80 B = 20 banks -> conflict-free b128 across 16 m-rows).
    __shared__ __align__(16) ushort_t Ah[2][7][32][40];   // h part, k = 0..223
    __shared__ __align__(16) ushort_t Ax[2][2][32][40];   // x part, k = 0..63

    const float* bih = dir ? bihB : bihF;
    const float* bhh = dir ? bhhB : bhhF;
    const ushort_t* wbase = Wpk + (long)dir * NTRI * 3 * KT_TOT * FRAG;
    __hip_bfloat16* hd = dir ? hbo : hfo;

    // biases per owned triple (tr selects triple wv + 7*tr)
    float br[2], bz[2], bnxv[2], bnhv[2];
    #pragma unroll
    for (int tr = 0; tr < 2; tr++) {
        int jl = 16 * (wv + 7 * tr) + c;
        bool val = jl < NH;
        br[tr]   = val ? bih[jl] + bhh[jl] : 0.0f;
        bz[tr]   = val ? bih[NH + jl] + bhh[NH + jl] : 0.0f;
        bnxv[tr] = val ? bih[2 * NH + jl] : 0.0f;
        bnhv[tr] = val ? bhh[2 * NH + jl] : 0.0f;
    }

    // zero-init LDS (Ah zero == h0; padding zones stay zero forever)
    for (int i2 = tid; i2 < 2 * 7 * 32 * 40 / 2; i2 += 448) ((uint*)Ah)[i2] = 0u;
    for (int i2 = tid; i2 < 2 * 2 * 32 * 40 / 2; i2 += 448) ((uint*)Ax)[i2] = 0u;

    // stage x for first step into Ax[0]
    {
        int tt0 = dir ? (NT - 1) : 0;
        const float* xs = x + ((long)tt0 * NS + s0) * NI;
        for (int e = tid; e < NPB * NI; e += 448) {
            int m = e / NI, dd = e - m * NI;
            Ax[0][dd >> 5][m][dd & 31] = f2b(xs[e]);
        }
    }
    __syncthreads();

    float hold[2][2][4] = {};   // [tr][mt][reg]

    for (int t = 0; t < NT; t++) {
        const int cur = t & 1, nxt = cur ^ 1;
        const int tt = dir ? (NT - 1 - t) : t;

        #pragma unroll
        for (int mt = 0; mt < 2; mt++) {
            const int m = mt * 16 + c;
            bf16x8 af[KT_TOT];
            af[0] = *(const bf16x8*)&Ax[cur][0][m][quad * 8];
            af[1] = *(const bf16x8*)&Ax[cur][1][m][quad * 8];
            #pragma unroll
            for (int kt = 0; kt < 7; kt++)
                af[2 + kt] = *(const bf16x8*)&Ah[cur][kt][m][quad * 8];

            #pragma unroll
            for (int tr = 0; tr < 2; tr++) {
                const ushort_t* wt = wbase + (wv + 7 * tr) * (3 * KT_TOT * FRAG) + ln * 8;
                f32x4 aR  = {0.0f, 0.0f, 0.0f, 0.0f};
                f32x4 aZ  = {0.0f, 0.0f, 0.0f, 0.0f};
                f32x4 aNX = {0.0f, 0.0f, 0.0f, 0.0f};
                f32x4 aNH = {0.0f, 0.0f, 0.0f, 0.0f};
                #pragma unroll
                for (int kt = 0; kt < KT_TOT; kt++) {
                    bf16x8 bR = *(const bf16x8*)(wt + (0 * KT_TOT + kt) * FRAG);
                    bf16x8 bZ = *(const bf16x8*)(wt + (1 * KT_TOT + kt) * FRAG);
                    bf16x8 bN = *(const bf16x8*)(wt + (2 * KT_TOT + kt) * FRAG);
                    aR = __builtin_amdgcn_mfma_f32_16x16x32_bf16(af[kt], bR, aR, 0, 0, 0);
                    aZ = __builtin_amdgcn_mfma_f32_16x16x32_bf16(af[kt], bZ, aZ, 0, 0, 0);
                    if (kt < 2) aNX = __builtin_amdgcn_mfma_f32_16x16x32_bf16(af[kt], bN, aNX, 0, 0, 0);
                    else        aNH = __builtin_amdgcn_mfma_f32_16x16x32_bf16(af[kt], bN, aNH, 0, 0, 0);
                }
                // activation + h update; C/D layout: row = quad*4+reg, col = c
                int jl = 16 * (wv + 7 * tr) + c;
                #pragma unroll
                for (int reg = 0; reg < 4; reg++) {
                    int mr = mt * 16 + quad * 4 + reg;
                    float r = sigf(aR[reg] + br[tr]);
                    float z = sigf(aZ[reg] + bz[tr]);
                    float n = tanh_fast(aNX[reg] + bnxv[tr] + r * (aNH[reg] + bnhv[tr]));
                    float hn = (1.0f - z) * n + z * hold[tr][mt][reg];
                    hold[tr][mt][reg] = hn;
                    ushort_t hb16 = f2b(hn);
                    if (mr < NPB) {
                        Ah[nxt][jl >> 5][mr][jl & 31] = hb16;
                        if (jl < NH)
                            hd[((long)(s0 + mr) * NT + tt) * NH + jl] = *(__hip_bfloat16*)&hb16;
                    }
                }
            }
        }

        // stage x for next step
        if (t < NT - 1) {
            int ttn = dir ? (NT - 2 - t) : (t + 1);
            const float* xs = x + ((long)ttn * NS + s0) * NI;
            for (int e = tid; e < NPB * NI; e += 448) {
                int m2 = e / NI, dd = e - m2 * NI;
                Ax[nxt][dd >> 5][m2][dd & 31] = f2b(xs[e]);
            }
        }
        __syncthreads();
    }
}

// ---------------------------------------------------------------------------
// Word-level attention: one block per sentence.
// ---------------------------------------------------------------------------
__global__ __launch_bounds__(256)
void attn_kernel(const __hip_bfloat16* __restrict__ hf, const __hip_bfloat16* __restrict__ hb,
                 const float* __restrict__ aw, float* __restrict__ H) {
    int s = blockIdx.x;
    int tid = threadIdx.x;
    __shared__ __align__(16) float tup[NT][NH];
    __shared__ float sc[NT];
    __shared__ float inv_s;
    const __hip_bfloat16* pf = hf + (long)s * NT * NH;
    const __hip_bfloat16* pb = hb + (long)s * NT * NH;
    for (int i = tid; i < NT * NH; i += 256)
        (&tup[0][0])[i] = __bfloat162float(pf[i]) + __bfloat162float(pb[i]);
    __syncthreads();
    int wvv = tid >> 6, lnn = tid & 63;
    for (int t = wvv; t < NT; t += 4) {
        float p = 0.0f;
        for (int j = lnn; j < NH; j += 64) p += tanh_fast(tup[t][j]) * aw[j];
        #pragma unroll
        for (int off = 32; off > 0; off >>= 1) p += __shfl_down(p, off, 64);
        if (lnn == 0) sc[t] = p;
    }
    __syncthreads();
    if (tid == 0) {
        float mx = sc[0];
        for (int t = 1; t < NT; t++) mx = fmaxf(mx, sc[t]);
        float sum = 0.0f;
        for (int t = 0; t < NT; t++) { float e = __expf(sc[t] - mx); sc[t] = e; sum += e; }
        inv_s = 1.0f / sum;
    }
    __syncthreads();
    float inv = inv_s;
    for (int j = tid; j < NH; j += 256) {
        float acc = 0.0f;
        #pragma unroll 7
        for (int t = 0; t < NT; t++) acc += sc[t] * tup[t][j];
        H[s * NH + j] = acc * inv;
    }
}

// ---------------------------------------------------------------------------
// Bag attention + logits + BCE loss.
// ---------------------------------------------------------------------------
__global__ __launch_bounds__(256)
void bag_kernel(const float* __restrict__ H, const int* __restrict__ label,
                const float* __restrict__ sen_a, const float* __restrict__ sen_r,
                const float* __restrict__ rel, const float* __restrict__ sen_d,
                float* __restrict__ out) {
    int b = blockIdx.x;
    int tid = threadIdx.x;
    __shared__ __align__(16) float Hs[NPB][NH];
    __shared__ float e[NPB];
    __shared__ float Sv[NH];
    __shared__ float part[4];
    const float* Hb = H + b * NPB * NH;
    for (int i = tid; i < NPB * NH; i += 256) (&Hs[0][0])[i] = Hb[i];
    __syncthreads();
    int wvv = tid >> 6, lnn = tid & 63;
    for (int n = wvv; n < NPB; n += 4) {
        float p = 0.0f;
        for (int j = lnn; j < NH; j += 64) p += Hs[n][j] * sen_a[j] * sen_r[j];
        #pragma unroll
        for (int off = 32; off > 0; off >>= 1) p += __shfl_down(p, off, 64);
        if (lnn == 0) e[n] = p;
    }
    __syncthreads();
    if (tid == 0) {
        float mx = e[0];
        for (int n = 1; n < NPB; n++) mx = fmaxf(mx, e[n]);
        float sum = 0.0f;
        for (int n = 0; n < NPB; n++) { float v = __expf(e[n] - mx); e[n] = v; sum += v; }
        float inv = 1.0f / sum;
        for (int n = 0; n < NPB; n++) e[n] *= inv;
    }
    __syncthreads();
    for (int j = tid; j < NH; j += 256) {
        float acc = 0.0f;
        #pragma unroll
        for (int n = 0; n < NPB; n++) acc += e[n] * Hs[n][j];
        Sv[j] = acc;
    }
    __syncthreads();
    float bce = 0.0f;
    if (tid < NREL) {
        float acc = 0.0f;
        #pragma unroll 4
        for (int j = 0; j < NH; j++) acc += Sv[j] * rel[tid * NH + j];
        float l = acc + sen_d[tid];
        out[1 + b * NREL + tid] = l;
        float tgt = (label[b] == tid) ? 1.0f : 0.0f;
        bce = fmaxf(l, 0.0f) - l * tgt + log1pf(__expf(-fabsf(l)));
    }
    #pragma unroll
    for (int off = 32; off > 0; off >>= 1) bce += __shfl_down(bce, off, 64);
    if (lnn == 0) part[wvv] = bce;
    __syncthreads();
    if (tid == 0) {
        float tot = (part[0] + part[1] + part[2] + part[3]) * (1.0f / NREL);
        atomicAdd(out, tot);
    }
}

// ---------------------------------------------------------------------------
extern "C" void kernel_launch(void* const* d_in, const int* in_sizes, int n_in,
                              void* d_out, int out_size, void* d_ws, size_t ws_size,
                              hipStream_t stream) {
    const int*   tok   = (const int*)d_in[0];
    const int*   p1    = (const int*)d_in[1];
    const int*   p2    = (const int*)d_in[2];
    const int*   label = (const int*)d_in[3];
    const float* emb   = (const float*)d_in[4];
    const float* pemb  = (const float*)d_in[5];
    const float* WihF  = (const float*)d_in[6];
    const float* WhhF  = (const float*)d_in[7];
    const float* bihF  = (const float*)d_in[8];
    const float* bhhF  = (const float*)d_in[9];
    const float* WihB  = (const float*)d_in[10];
    const float* WhhB  = (const float*)d_in[11];
    const float* bihB  = (const float*)d_in[12];
    const float* bhhB  = (const float*)d_in[13];
    const float* aw    = (const float*)d_in[14];
    const float* sen_a = (const float*)d_in[15];
    const float* sen_r = (const float*)d_in[16];
    const float* rel   = (const float*)d_in[17];
    const float* sen_d = (const float*)d_in[18];

    // workspace layout
    ushort_t* Wpk = (ushort_t*)d_ws;                       // 387,072 ushort (774,144 B)
    float* xbuf = (float*)(Wpk + 2 * NTRI * 3 * KT_TOT * FRAG);
    float* Hbuf = xbuf + (long)NT * NS * NI;               // 512,000 f
    __hip_bfloat16* hfb = (__hip_bfloat16*)(Hbuf + NS * NH);
    __hip_bfloat16* hbb = hfb + (long)NS * NT * NH;

    const int wpk_total = 2 * NTRI * 3 * KT_TOT * FRAG;
    prep_wpk_kernel<<<(wpk_total + 255) / 256, 256, 0, stream>>>(WihF, WhhF, WihB, WhhB, Wpk);
    gather_kernel<<<(NT * NS * NI + 255) / 256, 256, 0, stream>>>(tok, p1, p2, emb, pemb, xbuf);
    gru_kernel<<<256, 448, 0, stream>>>(xbuf, Wpk, bihF, bhhF, bihB, bhhB, hfb, hbb);
    attn_kernel<<<NS, 256, 0, stream>>>(hfb, hbb, aw, Hbuf);
    hipMemsetAsync(d_out, 0, sizeof(float), stream);
    bag_kernel<<<NBAG, 256, 0, stream>>>(Hbuf, label, sen_a, sen_r, rel, sen_d, (float*)d_out);
}

// Round 3
// 1057.205 us; speedup vs baseline: 5.9953x; 1.1490x over previous
//
#include <hip/hip_runtime.h>
#include <hip/hip_bf16.h>

// Problem constants
#define NS 2560      // B*N sentences
#define NT 70        // tokens per sentence
#define NH 200       // hidden
#define NI 60        // input dim (50 + 5 + 5)
#define NREL 100
#define NBAG 128
#define NPB 20       // sentences per bag

#define NTRI 13      // gate triples of 16 (13*16 = 208 >= 200)
#define KT_TOT 9     // K tiles of 32: 2 for x (60->64), 7 for h (200->224)
#define FRAG 512     // elements per B fragment (64 lanes x 8)

typedef unsigned short ushort_t;
typedef __attribute__((ext_vector_type(8))) short bf16x8;
typedef __attribute__((ext_vector_type(4))) float f32x4;

__device__ __forceinline__ float sigf(float x) { return 1.0f / (1.0f + __expf(-x)); }
__device__ __forceinline__ float tanh_fast(float x) {
    float e = __expf(2.0f * x);
    return 1.0f - 2.0f / (e + 1.0f);
}
__device__ __forceinline__ ushort_t f2b(float f) {
    __hip_bfloat16 h = __float2bfloat16(f);
    return *(ushort_t*)&h;
}
__device__ __forceinline__ float b2f(ushort_t u) {
    __hip_bfloat16 h = *(__hip_bfloat16*)&u;
    return __bfloat162float(h);
}

// ---------------------------------------------------------------------------
// Pack weights into MFMA B-fragment order, bf16, zero-padded:
//   Wpk[dir][tri (13)][kt (9)][seg (3: r,z,n)][lane (64)][j (8)]
// (kt outer, seg inner -> each wave streams 27 contiguous KB per step)
// B-frag for 16x16x32: lane ln holds B[k=(ln>>4)*8+j][n=ln&15];
// n -> gate g = seg*200 + 16*tri + (ln&15); kt<2: x-dim, kt>=2: h-dim.
// ---------------------------------------------------------------------------
__global__ void prep_wpk_kernel(const float* __restrict__ WihF, const float* __restrict__ WhhF,
                                const float* __restrict__ WihB, const float* __restrict__ WhhB,
                                ushort_t* __restrict__ Wpk) {
    int idx = blockIdx.x * 256 + threadIdx.x;
    const int total = 2 * NTRI * KT_TOT * 3 * FRAG;
    if (idx >= total) return;
    int j = idx & 7;
    int ln = (idx >> 3) & 63;
    int f = idx >> 9;
    int seg = f % 3;
    int kt = (f / 3) % KT_TOT;
    int tri = (f / 27) % NTRI;
    int d = f / (27 * NTRI);
    const float* Wih = d ? WihB : WihF;
    const float* Whh = d ? WhhB : WhhF;
    int gl = 16 * tri + (ln & 15);
    int kk = ((ln >> 4) << 3) + j;
    float v = 0.0f;
    if (gl < NH) {
        int g = seg * NH + gl;
        if (kt < 2) {
            int kx = kt * 32 + kk;
            if (kx < NI) v = Wih[g * NI + kx];
        } else {
            int kh = (kt - 2) * 32 + kk;
            if (kh < NH) v = Whh[g * NH + kh];
        }
    }
    Wpk[idx] = f2b(v);
}

// ---------------------------------------------------------------------------
// Gather x[t][s][d] = concat(word_emb, pos1_emb, pos2_emb), bf16, [70][2560][60]
// ---------------------------------------------------------------------------
__global__ void gather_kernel(const int* __restrict__ tok, const int* __restrict__ p1,
                              const int* __restrict__ p2, const float* __restrict__ emb,
                              const float* __restrict__ pemb, ushort_t* __restrict__ x) {
    int idx = blockIdx.x * 256 + threadIdx.x;
    if (idx >= NT * NS * NI) return;
    int d = idx % NI;
    int st = idx / NI;
    int s = st % NS;
    int t = st / NS;
    int o = s * NT + t;
    float v;
    if (d < 50)      v = emb[(long)tok[o] * 50 + d];
    else if (d < 55) v = pemb[p1[o] * 5 + (d - 50)];
    else             v = pemb[p2[o] * 5 + (d - 55)];
    x[idx] = f2b(v);
}

// ---------------------------------------------------------------------------
// MFMA GRU. 256 blocks (128 groups x 2 dirs), 832 threads = 13 waves.
// Wave w owns triple w = gates [16w, 16w+16) for r,z,n segments.
// Per step: each wave streams its 27 B-fragments ONCE (hoisted across both
// m-tiles) -> 351 KB/block-step from L2 (was 756). A (x||h) in LDS bf16,
// double-buffered; one barrier per step. h-update lane-local; h_old in regs.
// h output layout [t][s][j] -> full-line stores (no RMW fetch).
// ---------------------------------------------------------------------------
__global__ __launch_bounds__(832, 1)
void gru_kernel(const ushort_t* __restrict__ x, const ushort_t* __restrict__ Wpk,
                const float* __restrict__ bihF, const float* __restrict__ bhhF,
                const float* __restrict__ bihB, const float* __restrict__ bhhB,
                __hip_bfloat16* __restrict__ hfo, __hip_bfloat16* __restrict__ hbo) {
    const int dir = blockIdx.x >> 7;
    const int s0 = (blockIdx.x & 127) * NPB;
    const int tid = threadIdx.x;
    const int wv = tid >> 6, ln = tid & 63;
    const int c = ln & 15, quad = ln >> 4;
    const int jl = 16 * wv + c;          // gate column this lane owns (may be >=200)
    const bool jv = jl < NH;

    // A-operand buffers, row stride 40 ushorts (80 B).
    __shared__ __align__(16) ushort_t Ah[2][7][32][40];   // h part, k = 0..223
    __shared__ __align__(16) ushort_t Ax[2][2][32][40];   // x part, k = 0..63

    const float* bih = dir ? bihB : bihF;
    const float* bhh = dir ? bhhB : bhhF;
    const ushort_t* wt = Wpk + ((long)dir * NTRI + wv) * (27 * FRAG) + ln * 8;
    __hip_bfloat16* hd = dir ? hbo : hfo;

    const float br  = jv ? bih[jl] + bhh[jl] : 0.0f;
    const float bz  = jv ? bih[NH + jl] + bhh[NH + jl] : 0.0f;
    const float bnx = jv ? bih[2 * NH + jl] : 0.0f;
    const float bnh = jv ? bhh[2 * NH + jl] : 0.0f;

    // zero-init all LDS (h0 = 0; padding rows/cols stay zero forever)
    for (int i2 = tid; i2 < (2 * 7 * 32 * 40 + 2 * 2 * 32 * 40) / 2; i2 += 832)
        ((uint*)Ah)[i2] = 0u;   // Ax follows Ah contiguously? not guaranteed -> do separately
    __syncthreads();
    for (int i2 = tid; i2 < 2 * 2 * 32 * 40 / 2; i2 += 832)
        ((uint*)Ax)[i2] = 0u;

    // stage x for first step into Ax[0]: 600 threads x one uint (2 bf16)
    const bool stager = tid < 600;
    const int sm = stager ? (tid / 30) : 0;         // sentence row 0..19
    const int sdd = stager ? ((tid % 30) * 2) : 0;  // element 0..58 (even)
    if (stager) {
        int tt0 = dir ? (NT - 1) : 0;
        uint v = *(const uint*)(x + ((long)tt0 * NS + s0) * NI + sm * NI + sdd);
        *(uint*)&Ax[0][sdd >> 5][sm][sdd & 31] = v;
    }
    __syncthreads();

    float hold[2][4] = {};   // [mt][reg]

    for (int t = 0; t < NT; t++) {
        const int cur = t & 1, nxt = cur ^ 1;
        const int tt = dir ? (NT - 1 - t) : t;
        __hip_bfloat16* hdt = hd + (long)tt * NS * NH;

        // issue next-step x load early (latency overlapped with MFMA work)
        uint xv = 0;
        const bool st_now = stager && (t < NT - 1);
        if (st_now) {
            int ttn = dir ? (NT - 2 - t) : (t + 1);
            xv = *(const uint*)(x + ((long)ttn * NS + s0) * NI + sm * NI + sdd);
        }

        f32x4 aR[2], aZ[2], aNX[2], aNH[2];
        const f32x4 vz = {0.0f, 0.0f, 0.0f, 0.0f};
        aR[0] = aR[1] = aZ[0] = aZ[1] = vz;
        aNX[0] = aNX[1] = aNH[0] = aNH[1] = vz;

        #pragma unroll
        for (int kt = 0; kt < KT_TOT; kt++) {
            bf16x8 a0, a1;
            if (kt < 2) {
                a0 = *(const bf16x8*)&Ax[cur][kt][c][quad * 8];
                a1 = *(const bf16x8*)&Ax[cur][kt][16 + c][quad * 8];
            } else {
                a0 = *(const bf16x8*)&Ah[cur][kt - 2][c][quad * 8];
                a1 = *(const bf16x8*)&Ah[cur][kt - 2][16 + c][quad * 8];
            }
            bf16x8 bR = *(const bf16x8*)(wt + (kt * 3 + 0) * FRAG);
            bf16x8 bZ = *(const bf16x8*)(wt + (kt * 3 + 1) * FRAG);
            bf16x8 bN = *(const bf16x8*)(wt + (kt * 3 + 2) * FRAG);
            aR[0] = __builtin_amdgcn_mfma_f32_16x16x32_bf16(a0, bR, aR[0], 0, 0, 0);
            aR[1] = __builtin_amdgcn_mfma_f32_16x16x32_bf16(a1, bR, aR[1], 0, 0, 0);
            aZ[0] = __builtin_amdgcn_mfma_f32_16x16x32_bf16(a0, bZ, aZ[0], 0, 0, 0);
            aZ[1] = __builtin_amdgcn_mfma_f32_16x16x32_bf16(a1, bZ, aZ[1], 0, 0, 0);
            if (kt < 2) {
                aNX[0] = __builtin_amdgcn_mfma_f32_16x16x32_bf16(a0, bN, aNX[0], 0, 0, 0);
                aNX[1] = __builtin_amdgcn_mfma_f32_16x16x32_bf16(a1, bN, aNX[1], 0, 0, 0);
            } else {
                aNH[0] = __builtin_amdgcn_mfma_f32_16x16x32_bf16(a0, bN, aNH[0], 0, 0, 0);
                aNH[1] = __builtin_amdgcn_mfma_f32_16x16x32_bf16(a1, bN, aNH[1], 0, 0, 0);
            }
        }

        // activations + h update; C/D layout: row = quad*4+reg, col = c
        #pragma unroll
        for (int mt = 0; mt < 2; mt++) {
            #pragma unroll
            for (int reg = 0; reg < 4; reg++) {
                int mr = mt * 16 + quad * 4 + reg;
                float r = sigf(aR[mt][reg] + br);
                float z = sigf(aZ[mt][reg] + bz);
                float n = tanh_fast(aNX[mt][reg] + bnx + r * (aNH[mt][reg] + bnh));
                float hn = (1.0f - z) * n + z * hold[mt][reg];
                hold[mt][reg] = hn;
                if (mr < NPB && jv) {
                    ushort_t hb16 = f2b(hn);
                    Ah[nxt][jl >> 5][mr][jl & 31] = hb16;
                    hdt[(s0 + mr) * NH + jl] = *(__hip_bfloat16*)&hb16;
                }
            }
        }

        // complete next-step x staging
        if (st_now) *(uint*)&Ax[nxt][sdd >> 5][sm][sdd & 31] = xv;
        __syncthreads();
    }
}

// ---------------------------------------------------------------------------
// Word-level attention: one block per sentence. h layout is [t][s][j].
// ---------------------------------------------------------------------------
__global__ __launch_bounds__(256)
void attn_kernel(const __hip_bfloat16* __restrict__ hf, const __hip_bfloat16* __restrict__ hb,
                 const float* __restrict__ aw, float* __restrict__ H) {
    int s = blockIdx.x;
    int tid = threadIdx.x;
    __shared__ __align__(16) float tup[NT][NH];
    __shared__ float sc[NT];
    __shared__ float inv_s;
    for (int i = tid; i < NT * NH / 2; i += 256) {
        int t = i / 100, j2 = (i - t * 100) * 2;
        long off = ((long)t * NS + s) * NH + j2;
        uint uf = *(const uint*)(hf + off);
        uint ub = *(const uint*)(hb + off);
        tup[t][j2]     = b2f((ushort_t)(uf & 0xffff)) + b2f((ushort_t)(ub & 0xffff));
        tup[t][j2 + 1] = b2f((ushort_t)(uf >> 16))    + b2f((ushort_t)(ub >> 16));
    }
    __syncthreads();
    int wvv = tid >> 6, lnn = tid & 63;
    for (int t = wvv; t < NT; t += 4) {
        float p = 0.0f;
        for (int j = lnn; j < NH; j += 64) p += tanh_fast(tup[t][j]) * aw[j];
        #pragma unroll
        for (int off = 32; off > 0; off >>= 1) p += __shfl_down(p, off, 64);
        if (lnn == 0) sc[t] = p;
    }
    __syncthreads();
    if (tid == 0) {
        float mx = sc[0];
        for (int t = 1; t < NT; t++) mx = fmaxf(mx, sc[t]);
        float sum = 0.0f;
        for (int t = 0; t < NT; t++) { float e = __expf(sc[t] - mx); sc[t] = e; sum += e; }
        inv_s = 1.0f / sum;
    }
    __syncthreads();
    float inv = inv_s;
    for (int j = tid; j < NH; j += 256) {
        float acc = 0.0f;
        #pragma unroll 7
        for (int t = 0; t < NT; t++) acc += sc[t] * tup[t][j];
        H[s * NH + j] = acc * inv;
    }
}

// ---------------------------------------------------------------------------
// Bag attention + logits + BCE loss.
// ---------------------------------------------------------------------------
__global__ __launch_bounds__(256)
void bag_kernel(const float* __restrict__ H, const int* __restrict__ label,
                const float* __restrict__ sen_a, const float* __restrict__ sen_r,
                const float* __restrict__ rel, const float* __restrict__ sen_d,
                float* __restrict__ out) {
    int b = blockIdx.x;
    int tid = threadIdx.x;
    __shared__ __align__(16) float Hs[NPB][NH];
    __shared__ float e[NPB];
    __shared__ float Sv[NH];
    __shared__ float part[4];
    const float* Hb = H + b * NPB * NH;
    for (int i = tid; i < NPB * NH; i += 256) (&Hs[0][0])[i] = Hb[i];
    __syncthreads();
    int wvv = tid >> 6, lnn = tid & 63;
    for (int n = wvv; n < NPB; n += 4) {
        float p = 0.0f;
        for (int j = lnn; j < NH; j += 64) p += Hs[n][j] * sen_a[j] * sen_r[j];
        #pragma unroll
        for (int off = 32; off > 0; off >>= 1) p += __shfl_down(p, off, 64);
        if (lnn == 0) e[n] = p;
    }
    __syncthreads();
    if (tid == 0) {
        float mx = e[0];
        for (int n = 1; n < NPB; n++) mx = fmaxf(mx, e[n]);
        float sum = 0.0f;
        for (int n = 0; n < NPB; n++) { float v = __expf(e[n] - mx); e[n] = v; sum += v; }
        float inv = 1.0f / sum;
        for (int n = 0; n < NPB; n++) e[n] *= inv;
    }
    __syncthreads();
    for (int j = tid; j < NH; j += 256) {
        float acc = 0.0f;
        #pragma unroll
        for (int n = 0; n < NPB; n++) acc += e[n] * Hs[n][j];
        Sv[j] = acc;
    }
    __syncthreads();
    float bce = 0.0f;
    if (tid < NREL) {
        float acc = 0.0f;
        #pragma unroll 4
        for (int j = 0; j < NH; j++) acc += Sv[j] * rel[tid * NH + j];
        float l = acc + sen_d[tid];
        out[1 + b * NREL + tid] = l;
        float tgt = (label[b] == tid) ? 1.0f : 0.0f;
        bce = fmaxf(l, 0.0f) - l * tgt + log1pf(__expf(-fabsf(l)));
    }
    #pragma unroll
    for (int off = 32; off > 0; off >>= 1) bce += __shfl_down(bce, off, 64);
    if (lnn == 0) part[wvv] = bce;
    __syncthreads();
    if (tid == 0) {
        float tot = (part[0] + part[1] + part[2] + part[3]) * (1.0f / NREL);
        atomicAdd(out, tot);
    }
}

// ---------------------------------------------------------------------------
extern "C" void kernel_launch(void* const* d_in, const int* in_sizes, int n_in,
                              void* d_out, int out_size, void* d_ws, size_t ws_size,
                              hipStream_t stream) {
    const int*   tok   = (const int*)d_in[0];
    const int*   p1    = (const int*)d_in[1];
    const int*   p2    = (const int*)d_in[2];
    const int*   label = (const int*)d_in[3];
    const float* emb   = (const float*)d_in[4];
    const float* pemb  = (const float*)d_in[5];
    const float* WihF  = (const float*)d_in[6];
    const float* WhhF  = (const float*)d_in[7];
    const float* bihF  = (const float*)d_in[8];
    const float* bhhF  = (const float*)d_in[9];
    const float* WihB  = (const float*)d_in[10];
    const float* WhhB  = (const float*)d_in[11];
    const float* bihB  = (const float*)d_in[12];
    const float* bhhB  = (const float*)d_in[13];
    const float* aw    = (const float*)d_in[14];
    const float* sen_a = (const float*)d_in[15];
    const float* sen_r = (const float*)d_in[16];
    const float* rel   = (const float*)d_in[17];
    const float* sen_d = (const float*)d_in[18];

    // workspace layout
    const int wpk_total = 2 * NTRI * KT_TOT * 3 * FRAG;   // 359,424 ushorts
    ushort_t* Wpk  = (ushort_t*)d_ws;
    ushort_t* xbuf = Wpk + wpk_total;                      // [70][2560][60] bf16
    float* Hbuf = (float*)(xbuf + (long)NT * NS * NI);     // 512,000 f
    __hip_bfloat16* hfb = (__hip_bfloat16*)(Hbuf + NS * NH);   // [t][s][j]
    __hip_bfloat16* hbb = hfb + (long)NT * NS * NH;            // [t][s][j]

    prep_wpk_kernel<<<(wpk_total + 255) / 256, 256, 0, stream>>>(WihF, WhhF, WihB, WhhB, Wpk);
    gather_kernel<<<(NT * NS * NI + 255) / 256, 256, 0, stream>>>(tok, p1, p2, emb, pemb, xbuf);
    gru_kernel<<<256, 832, 0, stream>>>(xbuf, Wpk, bihF, bhhF, bihB, bhhB, hfb, hbb);
    attn_kernel<<<NS, 256, 0, stream>>>(hfb, hbb, aw, Hbuf);
    hipMemsetAsync(d_out, 0, sizeof(float), stream);
    bag_kernel<<<NBAG, 256, 0, stream>>>(Hbuf, label, sen_a, sen_r, rel, sen_d, (float*)d_out);
}

// Round 4
// 713.507 us; speedup vs baseline: 8.8833x; 1.4817x over previous
//
#include <hip/hip_runtime.h>
#include <hip/hip_bf16.h>

// Problem constants
#define NS 2560      // B*N sentences
#define NT 70        // tokens per sentence
#define NH 200       // hidden
#define NHP 208      // padded h row stride (32B-aligned rows for bf16 stores)
#define NI 60        // input dim (50 + 5 + 5)
#define NREL 100
#define NBAG 128
#define NPB 20       // sentences per bag

#define NTRI 13      // gate triples of 16 (13*16 = 208 >= 200)
#define KT_TOT 9     // K tiles of 32: 2 for x (60->64), 7 for h (200->224)
#define FRAG 512     // bytes per fp8 B fragment (64 lanes x 8)

typedef unsigned short ushort_t;
typedef unsigned char uchar_t;
typedef __attribute__((ext_vector_type(4))) float f32x4;
typedef int v2i __attribute__((ext_vector_type(2), aligned(4)));

__device__ __forceinline__ float sigf(float x) { return 1.0f / (1.0f + __expf(-x)); }
__device__ __forceinline__ float tanh_fast(float x) {
    float e = __expf(2.0f * x);
    return 1.0f - 2.0f / (e + 1.0f);
}
__device__ __forceinline__ ushort_t f2b(float f) {
    __hip_bfloat16 h = __float2bfloat16(f);
    return *(ushort_t*)&h;
}
__device__ __forceinline__ float b2f(ushort_t u) {
    __hip_bfloat16 h = *(__hip_bfloat16*)&u;
    return __bfloat162float(h);
}

// fp8 e4m3 (OCP on gfx950) encode, RTNE
__device__ __forceinline__ uchar_t f2fp8(float f) {
#if __has_builtin(__builtin_amdgcn_cvt_pk_fp8_f32)
    int p = __builtin_amdgcn_cvt_pk_fp8_f32(f, f, 0, false);
    return (uchar_t)(p & 0xff);
#else
    unsigned u = __float_as_uint(f);
    unsigned s = (u >> 24) & 0x80u;
    float a = fabsf(f);
    if (a >= 448.0f) return (uchar_t)(s | 0x7E);
    if (a < 0.015625f) {                      // subnormal range [0, 2^-6)
        int q = (int)rintf(a * 512.0f);       // 0..8 (8 rolls into normal 2^-6)
        return (uchar_t)(s | (unsigned)q);
    }
    unsigned au = __float_as_uint(a);
    int e = (int)(au >> 23) - 127;
    unsigned m = au & 0x7fffffu;
    unsigned keep = m >> 20;
    unsigned rnd = (m >> 19) & 1u;
    unsigned sticky = (m & 0x7ffffu) ? 1u : 0u;
    keep += (rnd & (sticky | (keep & 1u)));
    int ee = e + 7;
    if (keep == 8u) { keep = 0u; ee += 1; }
    if (ee >= 16) return (uchar_t)(s | 0x7E);
    return (uchar_t)(s | ((unsigned)ee << 3) | keep);
#endif
}

__device__ __forceinline__ long ld_long_a4(const void* p) {
    v2i v = *(const v2i*)p;
    long r; __builtin_memcpy(&r, &v, 8); return r;
}

// ---------------------------------------------------------------------------
// Pack weights into MFMA B-fragment order, fp8 e4m3, zero-padded:
//   Wpk[dir][tri (13)][kt (9)][seg (3: r,z,n)][lane (64)][j (8)]  (bytes)
// B-frag for 16x16x32: lane ln holds B[k=(ln>>4)*8+j][n=ln&15];
// n -> gate g = seg*200 + 16*tri + (ln&15); kt<2: x-dim, kt>=2: h-dim.
// Any (quad,j)->k permutation is harmless as long as A uses the same map.
// ---------------------------------------------------------------------------
__global__ void prep_wpk_kernel(const float* __restrict__ WihF, const float* __restrict__ WhhF,
                                const float* __restrict__ WihB, const float* __restrict__ WhhB,
                                uchar_t* __restrict__ Wpk) {
    int idx = blockIdx.x * 256 + threadIdx.x;
    const int total = 2 * NTRI * KT_TOT * 3 * FRAG;
    if (idx >= total) return;
    int j = idx & 7;
    int ln = (idx >> 3) & 63;
    int f = idx >> 9;
    int seg = f % 3;
    int kt = (f / 3) % KT_TOT;
    int tri = (f / 27) % NTRI;
    int d = f / (27 * NTRI);
    const float* Wih = d ? WihB : WihF;
    const float* Whh = d ? WhhB : WhhF;
    int gl = 16 * tri + (ln & 15);
    int kk = ((ln >> 4) << 3) + j;
    float v = 0.0f;
    if (gl < NH) {
        int g = seg * NH + gl;
        if (kt < 2) {
            int kx = kt * 32 + kk;
            if (kx < NI) v = Wih[g * NI + kx];
        } else {
            int kh = (kt - 2) * 32 + kk;
            if (kh < NH) v = Whh[g * NH + kh];
        }
    }
    Wpk[idx] = f2fp8(v);
}

// ---------------------------------------------------------------------------
// Gather x[t][s][d] = concat(word_emb, pos1_emb, pos2_emb), fp8, [70][2560][60]
// 4 elements per thread, packed uint store.
// ---------------------------------------------------------------------------
__global__ void gather_kernel(const int* __restrict__ tok, const int* __restrict__ p1,
                              const int* __restrict__ p2, const float* __restrict__ emb,
                              const float* __restrict__ pemb, uchar_t* __restrict__ x) {
    int idx = blockIdx.x * 256 + threadIdx.x;
    if (idx >= NT * NS * 15) return;
    int chunk = idx % 15;
    int st = idx / 15;
    int s = st % NS;
    int t = st / NS;
    int o = s * NT + t;
    int d4 = chunk * 4;
    unsigned out = 0;
    #pragma unroll
    for (int e = 0; e < 4; e++) {
        int d = d4 + e;
        float v;
        if (d < 50)      v = emb[(long)tok[o] * 50 + d];
        else if (d < 55) v = pemb[p1[o] * 5 + (d - 50)];
        else             v = pemb[p2[o] * 5 + (d - 55)];
        out |= ((unsigned)f2fp8(v)) << (8 * e);
    }
    *(unsigned*)(x + ((long)t * NS + s) * NI + d4) = out;
}

// ---------------------------------------------------------------------------
// MFMA GRU, register-resident weights. 256 blocks (128 groups x 2 dirs),
// 832 threads = 13 waves. Wave w owns triple w = gates [16w,16w+16) r,z,n.
// All 27 B-fragments (fp8) preloaded into 54 VGPRs/wave; K-loop has ZERO
// global loads. A: x-part read from global (L1-resident), h-part in LDS fp8
// (40B row stride, conflict-free b64 frag reads), double-buffered.
// h-update lane-local; h_old in regs; global h stores nontemporal, [t][s][208].
// ---------------------------------------------------------------------------
__global__ __launch_bounds__(832, 4)
void gru_kernel(const uchar_t* __restrict__ x, const uchar_t* __restrict__ Wpk,
                const float* __restrict__ bihF, const float* __restrict__ bhhF,
                const float* __restrict__ bihB, const float* __restrict__ bhhB,
                ushort_t* __restrict__ hfo, ushort_t* __restrict__ hbo) {
    const int dir = blockIdx.x >> 7;
    const int s0 = (blockIdx.x & 127) * NPB;
    const int tid = threadIdx.x;
    const int wv = tid >> 6, ln = tid & 63;
    const int c = ln & 15, quad = ln >> 4;
    const int jl = 16 * wv + c;          // gate column this lane owns (<208)
    const bool jv = jl < NH;

    // h A-operand double buffer, fp8. Row stride 40 B: b64 reads conflict-free.
    __shared__ __align__(16) uchar_t Ah[2][7][32][40];

    const float* bih = dir ? bihB : bihF;
    const float* bhh = dir ? bhhB : bhhF;
    ushort_t* hd = dir ? hbo : hfo;

    const float br  = jv ? bih[jl] + bhh[jl] : 0.0f;
    const float bz  = jv ? bih[NH + jl] + bhh[NH + jl] : 0.0f;
    const float bnx = jv ? bih[2 * NH + jl] : 0.0f;
    const float bnh = jv ? bhh[2 * NH + jl] : 0.0f;

    // ---- preload ALL B fragments for this wave's triple: 27 x 8 B = 54 VGPRs
    long Bf[27];
    {
        const uchar_t* wt = Wpk + ((long)(dir * NTRI + wv)) * (27 * FRAG) + ln * 8;
        #pragma unroll
        for (int i = 0; i < 27; i++) Bf[i] = *(const long*)(wt + i * FRAG);
    }

    // zero-init Ah (h0 = 0; padding rows/cols stay zero forever)
    for (int i2 = tid; i2 < (int)sizeof(Ah) / 4; i2 += 832) ((unsigned*)Ah)[i2] = 0u;
    __syncthreads();

    float hold[2][4] = {};   // [mt][reg]

    for (int t = 0; t < NT; t++) {
        const int cur = t & 1, nxt = cur ^ 1;
        const int tt = dir ? (NT - 1 - t) : t;

        // x A-fragments straight from global (k-map: k = quad*8 + j)
        const uchar_t* xp = x + ((long)tt * NS + s0) * NI;
        long ax00 = ld_long_a4(xp + c * NI + quad * 8);               // mt0, kt0
        long ax01 = ld_long_a4(xp + c * NI + 32 + quad * 8);          // mt0, kt1
        long ax10 = ld_long_a4(xp + (16 + c) * NI + quad * 8);        // mt1, kt0
        long ax11 = ld_long_a4(xp + (16 + c) * NI + 32 + quad * 8);   // mt1, kt1

        f32x4 aR[2], aZ[2], aNX[2], aNH[2];
        const f32x4 vz = {0.0f, 0.0f, 0.0f, 0.0f};
        aR[0] = aR[1] = aZ[0] = aZ[1] = vz;
        aNX[0] = aNX[1] = aNH[0] = aNH[1] = vz;

        // x contribution (kt 0,1)
        aR[0]  = __builtin_amdgcn_mfma_f32_16x16x32_fp8_fp8(ax00, Bf[0], aR[0], 0, 0, 0);
        aR[1]  = __builtin_amdgcn_mfma_f32_16x16x32_fp8_fp8(ax10, Bf[0], aR[1], 0, 0, 0);
        aZ[0]  = __builtin_amdgcn_mfma_f32_16x16x32_fp8_fp8(ax00, Bf[1], aZ[0], 0, 0, 0);
        aZ[1]  = __builtin_amdgcn_mfma_f32_16x16x32_fp8_fp8(ax10, Bf[1], aZ[1], 0, 0, 0);
        aNX[0] = __builtin_amdgcn_mfma_f32_16x16x32_fp8_fp8(ax00, Bf[2], aNX[0], 0, 0, 0);
        aNX[1] = __builtin_amdgcn_mfma_f32_16x16x32_fp8_fp8(ax10, Bf[2], aNX[1], 0, 0, 0);
        aR[0]  = __builtin_amdgcn_mfma_f32_16x16x32_fp8_fp8(ax01, Bf[3], aR[0], 0, 0, 0);
        aR[1]  = __builtin_amdgcn_mfma_f32_16x16x32_fp8_fp8(ax11, Bf[3], aR[1], 0, 0, 0);
        aZ[0]  = __builtin_amdgcn_mfma_f32_16x16x32_fp8_fp8(ax01, Bf[4], aZ[0], 0, 0, 0);
        aZ[1]  = __builtin_amdgcn_mfma_f32_16x16x32_fp8_fp8(ax11, Bf[4], aZ[1], 0, 0, 0);
        aNX[0] = __builtin_amdgcn_mfma_f32_16x16x32_fp8_fp8(ax01, Bf[5], aNX[0], 0, 0, 0);
        aNX[1] = __builtin_amdgcn_mfma_f32_16x16x32_fp8_fp8(ax11, Bf[5], aNX[1], 0, 0, 0);

        // h contribution (kt 2..8) from LDS
        #pragma unroll
        for (int kt = 0; kt < 7; kt++) {
            long ah0 = *(const long*)&Ah[cur][kt][c][quad * 8];
            long ah1 = *(const long*)&Ah[cur][kt][16 + c][quad * 8];
            aR[0]  = __builtin_amdgcn_mfma_f32_16x16x32_fp8_fp8(ah0, Bf[6 + kt * 3 + 0], aR[0], 0, 0, 0);
            aR[1]  = __builtin_amdgcn_mfma_f32_16x16x32_fp8_fp8(ah1, Bf[6 + kt * 3 + 0], aR[1], 0, 0, 0);
            aZ[0]  = __builtin_amdgcn_mfma_f32_16x16x32_fp8_fp8(ah0, Bf[6 + kt * 3 + 1], aZ[0], 0, 0, 0);
            aZ[1]  = __builtin_amdgcn_mfma_f32_16x16x32_fp8_fp8(ah1, Bf[6 + kt * 3 + 1], aZ[1], 0, 0, 0);
            aNH[0] = __builtin_amdgcn_mfma_f32_16x16x32_fp8_fp8(ah0, Bf[6 + kt * 3 + 2], aNH[0], 0, 0, 0);
            aNH[1] = __builtin_amdgcn_mfma_f32_16x16x32_fp8_fp8(ah1, Bf[6 + kt * 3 + 2], aNH[1], 0, 0, 0);
        }

        // activations + h update; C/D layout: row = quad*4+reg, col = c
        ushort_t* hdt = hd + (long)tt * NS * NHP;
        #pragma unroll
        for (int mt = 0; mt < 2; mt++) {
            #pragma unroll
            for (int reg = 0; reg < 4; reg++) {
                int mr = mt * 16 + quad * 4 + reg;
                float r = sigf(aR[mt][reg] + br);
                float z = sigf(aZ[mt][reg] + bz);
                float n = tanh_fast(aNX[mt][reg] + bnx + r * (aNH[mt][reg] + bnh));
                float hn = (1.0f - z) * n + z * hold[mt][reg];
                hold[mt][reg] = hn;
                if (mr < NPB && jv) {
                    Ah[nxt][jl >> 5][mr][jl & 31] = f2fp8(hn);
                    __builtin_nontemporal_store(f2b(hn), hdt + (s0 + mr) * NHP + jl);
                }
            }
        }
        __syncthreads();
    }
}

// ---------------------------------------------------------------------------
// Word-level attention: one block per sentence. h layout is [t][s][NHP] bf16.
// ---------------------------------------------------------------------------
__global__ __launch_bounds__(256)
void attn_kernel(const ushort_t* __restrict__ hf, const ushort_t* __restrict__ hb,
                 const float* __restrict__ aw, float* __restrict__ H) {
    int s = blockIdx.x;
    int tid = threadIdx.x;
    __shared__ __align__(16) float tup[NT][NH];
    __shared__ float sc[NT];
    __shared__ float inv_s;
    for (int i = tid; i < NT * NH / 2; i += 256) {
        int t = i / 100, j2 = (i - t * 100) * 2;
        long off = ((long)t * NS + s) * NHP + j2;
        unsigned uf = *(const unsigned*)(hf + off);
        unsigned ub = *(const unsigned*)(hb + off);
        tup[t][j2]     = b2f((ushort_t)(uf & 0xffff)) + b2f((ushort_t)(ub & 0xffff));
        tup[t][j2 + 1] = b2f((ushort_t)(uf >> 16))    + b2f((ushort_t)(ub >> 16));
    }
    __syncthreads();
    int wvv = tid >> 6, lnn = tid & 63;
    for (int t = wvv; t < NT; t += 4) {
        float p = 0.0f;
        for (int j = lnn; j < NH; j += 64) p += tanh_fast(tup[t][j]) * aw[j];
        #pragma unroll
        for (int off = 32; off > 0; off >>= 1) p += __shfl_down(p, off, 64);
        if (lnn == 0) sc[t] = p;
    }
    __syncthreads();
    if (tid == 0) {
        float mx = sc[0];
        for (int t = 1; t < NT; t++) mx = fmaxf(mx, sc[t]);
        float sum = 0.0f;
        for (int t = 0; t < NT; t++) { float e = __expf(sc[t] - mx); sc[t] = e; sum += e; }
        inv_s = 1.0f / sum;
    }
    __syncthreads();
    float inv = inv_s;
    for (int j = tid; j < NH; j += 256) {
        float acc = 0.0f;
        #pragma unroll 7
        for (int t = 0; t < NT; t++) acc += sc[t] * tup[t][j];
        H[s * NH + j] = acc * inv;
    }
}

// ---------------------------------------------------------------------------
// Bag attention + logits + BCE loss.
// ---------------------------------------------------------------------------
__global__ __launch_bounds__(256)
void bag_kernel(const float* __restrict__ H, const int* __restrict__ label,
                const float* __restrict__ sen_a, const float* __restrict__ sen_r,
                const float* __restrict__ rel, const float* __restrict__ sen_d,
                float* __restrict__ out) {
    int b = blockIdx.x;
    int tid = threadIdx.x;
    __shared__ __align__(16) float Hs[NPB][NH];
    __shared__ float e[NPB];
    __shared__ float Sv[NH];
    __shared__ float part[4];
    const float* Hb = H + b * NPB * NH;
    for (int i = tid; i < NPB * NH; i += 256) (&Hs[0][0])[i] = Hb[i];
    __syncthreads();
    int wvv = tid >> 6, lnn = tid & 63;
    for (int n = wvv; n < NPB; n += 4) {
        float p = 0.0f;
        for (int j = lnn; j < NH; j += 64) p += Hs[n][j] * sen_a[j] * sen_r[j];
        #pragma unroll
        for (int off = 32; off > 0; off >>= 1) p += __shfl_down(p, off, 64);
        if (lnn == 0) e[n] = p;
    }
    __syncthreads();
    if (tid == 0) {
        float mx = e[0];
        for (int n = 1; n < NPB; n++) mx = fmaxf(mx, e[n]);
        float sum = 0.0f;
        for (int n = 0; n < NPB; n++) { float v = __expf(e[n] - mx); e[n] = v; sum += v; }
        float inv = 1.0f / sum;
        for (int n = 0; n < NPB; n++) e[n] *= inv;
    }
    __syncthreads();
    for (int j = tid; j < NH; j += 256) {
        float acc = 0.0f;
        #pragma unroll
        for (int n = 0; n < NPB; n++) acc += e[n] * Hs[n][j];
        Sv[j] = acc;
    }
    __syncthreads();
    float bce = 0.0f;
    if (tid < NREL) {
        float acc = 0.0f;
        #pragma unroll 4
        for (int j = 0; j < NH; j++) acc += Sv[j] * rel[tid * NH + j];
        float l = acc + sen_d[tid];
        out[1 + b * NREL + tid] = l;
        float tgt = (label[b] == tid) ? 1.0f : 0.0f;
        bce = fmaxf(l, 0.0f) - l * tgt + log1pf(__expf(-fabsf(l)));
    }
    #pragma unroll
    for (int off = 32; off > 0; off >>= 1) bce += __shfl_down(bce, off, 64);
    if (lnn == 0) part[wvv] = bce;
    __syncthreads();
    if (tid == 0) {
        float tot = (part[0] + part[1] + part[2] + part[3]) * (1.0f / NREL);
        atomicAdd(out, tot);
    }
}

// ---------------------------------------------------------------------------
extern "C" void kernel_launch(void* const* d_in, const int* in_sizes, int n_in,
                              void* d_out, int out_size, void* d_ws, size_t ws_size,
                              hipStream_t stream) {
    const int*   tok   = (const int*)d_in[0];
    const int*   p1    = (const int*)d_in[1];
    const int*   p2    = (const int*)d_in[2];
    const int*   label = (const int*)d_in[3];
    const float* emb   = (const float*)d_in[4];
    const float* pemb  = (const float*)d_in[5];
    const float* WihF  = (const float*)d_in[6];
    const float* WhhF  = (const float*)d_in[7];
    const float* bihF  = (const float*)d_in[8];
    const float* bhhF  = (const float*)d_in[9];
    const float* WihB  = (const float*)d_in[10];
    const float* WhhB  = (const float*)d_in[11];
    const float* bihB  = (const float*)d_in[12];
    const float* bhhB  = (const float*)d_in[13];
    const float* aw    = (const float*)d_in[14];
    const float* sen_a = (const float*)d_in[15];
    const float* sen_r = (const float*)d_in[16];
    const float* rel   = (const float*)d_in[17];
    const float* sen_d = (const float*)d_in[18];

    // workspace layout (all 16B-aligned chunks)
    const long wpk_bytes = 2L * NTRI * KT_TOT * 3 * FRAG;      // 359,424
    const long x_bytes   = (long)NT * NS * NI + 1088;          // fp8 + OOB slack
    uchar_t* Wpk  = (uchar_t*)d_ws;
    uchar_t* xbuf = Wpk + wpk_bytes;
    float*   Hbuf = (float*)(xbuf + ((x_bytes + 15) & ~15L));  // 2560*200 f32
    ushort_t* hfb = (ushort_t*)(Hbuf + NS * NH);               // [t][s][NHP] bf16
    ushort_t* hbb = hfb + (long)NT * NS * NHP;

    prep_wpk_kernel<<<(int)((wpk_bytes + 255) / 256), 256, 0, stream>>>(WihF, WhhF, WihB, WhhB, Wpk);
    gather_kernel<<<(NT * NS * 15 + 255) / 256, 256, 0, stream>>>(tok, p1, p2, emb, pemb, xbuf);
    gru_kernel<<<256, 832, 0, stream>>>(xbuf, Wpk, bihF, bhhF, bihB, bhhB, hfb, hbb);
    attn_kernel<<<NS, 256, 0, stream>>>(hfb, hbb, aw, Hbuf);
    hipMemsetAsync(d_out, 0, sizeof(float), stream);
    bag_kernel<<<NBAG, 256, 0, stream>>>(Hbuf, label, sen_a, sen_r, rel, sen_d, (float*)d_out);
}

// Round 5
// 662.197 us; speedup vs baseline: 9.5716x; 1.0775x over previous
//
#include <hip/hip_runtime.h>
#include <hip/hip_bf16.h>

// Problem constants
#define NS 2560      // B*N sentences
#define NT 70        // tokens per sentence
#define NH 200       // hidden
#define NHP 208      // padded h row stride (32B-aligned rows for bf16 stores)
#define NI 60        // input dim (50 + 5 + 5)
#define NREL 100
#define NBAG 128
#define NPB 20       // sentences per bag

#define NTRI 13      // gate triples of 16 (13*16 = 208 >= 200)
#define FRAG 512     // bytes per fp8 B fragment (64 lanes x 8)

// Packed weight layout per dir: [ h-part: [tri][kt7=7][seg=3][512] = 139,776 B ]
//                               [ x-part: [tri][kt2=2][seg=3][512] =  39,936 B ]
#define WPK_H_BYTES (NTRI * 7 * 3 * FRAG)     // 139,776
#define WPK_X_BYTES (NTRI * 2 * 3 * FRAG)     //  39,936
#define WPK_DIR_BYTES (WPK_H_BYTES + WPK_X_BYTES)
// GRU LDS: Bh (139,776) + Ah dbuf (2*7*32*40 = 17,920) = 157,696 <= 160 KiB
#define GRU_LDS_BYTES (WPK_H_BYTES + 2 * 7 * 32 * 40)

typedef unsigned short ushort_t;
typedef unsigned char uchar_t;
typedef __attribute__((ext_vector_type(4))) float f32x4;
typedef int v2i __attribute__((ext_vector_type(2), aligned(4)));
typedef unsigned int v4u __attribute__((ext_vector_type(4), aligned(16)));

__device__ __forceinline__ float sigf(float x) { return 1.0f / (1.0f + __expf(-x)); }
__device__ __forceinline__ float tanh_fast(float x) {
    float e = __expf(2.0f * x);
    return 1.0f - 2.0f / (e + 1.0f);
}
__device__ __forceinline__ ushort_t f2b(float f) {
    __hip_bfloat16 h = __float2bfloat16(f);
    return *(ushort_t*)&h;
}
__device__ __forceinline__ float b2f(ushort_t u) {
    __hip_bfloat16 h = *(__hip_bfloat16*)&u;
    return __bfloat162float(h);
}

// fp8 e4m3 (OCP on gfx950) encode, RTNE
__device__ __forceinline__ uchar_t f2fp8(float f) {
#if __has_builtin(__builtin_amdgcn_cvt_pk_fp8_f32)
    int p = __builtin_amdgcn_cvt_pk_fp8_f32(f, f, 0, false);
    return (uchar_t)(p & 0xff);
#else
    unsigned u = __float_as_uint(f);
    unsigned s = (u >> 24) & 0x80u;
    float a = fabsf(f);
    if (a >= 448.0f) return (uchar_t)(s | 0x7E);
    if (a < 0.015625f) {
        int q = (int)rintf(a * 512.0f);
        return (uchar_t)(s | (unsigned)q);
    }
    unsigned au = __float_as_uint(a);
    int e = (int)(au >> 23) - 127;
    unsigned m = au & 0x7fffffu;
    unsigned keep = m >> 20;
    unsigned rnd = (m >> 19) & 1u;
    unsigned sticky = (m & 0x7ffffu) ? 1u : 0u;
    keep += (rnd & (sticky | (keep & 1u)));
    int ee = e + 7;
    if (keep == 8u) { keep = 0u; ee += 1; }
    if (ee >= 16) return (uchar_t)(s | 0x7E);
    return (uchar_t)(s | ((unsigned)ee << 3) | keep);
#endif
}

__device__ __forceinline__ long ld_long_a4(const void* p) {
    v2i v = *(const v2i*)p;
    long r; __builtin_memcpy(&r, &v, 8); return r;
}

// ---------------------------------------------------------------------------
// Pack weights into MFMA B-fragment order, fp8 e4m3, zero-padded.
// Per dir: h-part first (LDS-bulk-copyable), then x-part.
// B-frag for 16x16x32: lane ln holds B[k=(ln>>4)*8+j][n=ln&15];
// n -> gate g = seg*200 + 16*tri + (ln&15).
// ---------------------------------------------------------------------------
__global__ void prep_wpk_kernel(const float* __restrict__ WihF, const float* __restrict__ WhhF,
                                const float* __restrict__ WihB, const float* __restrict__ WhhB,
                                uchar_t* __restrict__ Wpk) {
    int idx = blockIdx.x * 256 + threadIdx.x;
    const int total = 2 * WPK_DIR_BYTES;
    if (idx >= total) return;
    int d = idx / WPK_DIR_BYTES;
    int r = idx - d * WPK_DIR_BYTES;
    int tri, ktg, seg, e;
    if (r < WPK_H_BYTES) {
        tri = r / 10752;
        int r2 = r % 10752;
        ktg = 2 + r2 / 1536;
        seg = (r2 % 1536) / 512;
        e = r2 % 512;
    } else {
        int r2 = r - WPK_H_BYTES;
        tri = r2 / 3072;
        int r3 = r2 % 3072;
        ktg = r3 / 1536;
        seg = (r3 % 1536) / 512;
        e = r3 % 512;
    }
    int j = e & 7;
    int ln = e >> 3;
    const float* Wih = d ? WihB : WihF;
    const float* Whh = d ? WhhB : WhhF;
    int gl = 16 * tri + (ln & 15);
    int kk = ((ln >> 4) << 3) + j;
    float v = 0.0f;
    if (gl < NH) {
        int g = seg * NH + gl;
        if (ktg < 2) {
            int kx = ktg * 32 + kk;
            if (kx < NI) v = Wih[g * NI + kx];
        } else {
            int kh = (ktg - 2) * 32 + kk;
            if (kh < NH) v = Whh[g * NH + kh];
        }
    }
    Wpk[idx] = f2fp8(v);
}

// ---------------------------------------------------------------------------
// Gather x[t][s][d] = concat(word_emb, pos1_emb, pos2_emb), fp8, [70][2560][60]
// ---------------------------------------------------------------------------
__global__ void gather_kernel(const int* __restrict__ tok, const int* __restrict__ p1,
                              const int* __restrict__ p2, const float* __restrict__ emb,
                              const float* __restrict__ pemb, uchar_t* __restrict__ x) {
    int idx = blockIdx.x * 256 + threadIdx.x;
    if (idx >= NT * NS * 15) return;
    int chunk = idx % 15;
    int st = idx / 15;
    int s = st % NS;
    int t = st / NS;
    int o = s * NT + t;
    int d4 = chunk * 4;
    unsigned out = 0;
    #pragma unroll
    for (int e = 0; e < 4; e++) {
        int d = d4 + e;
        float v;
        if (d < 50)      v = emb[(long)tok[o] * 50 + d];
        else if (d < 55) v = pemb[p1[o] * 5 + (d - 50)];
        else             v = pemb[p2[o] * 5 + (d - 55)];
        out |= ((unsigned)f2fp8(v)) << (8 * e);
    }
    *(unsigned*)(x + ((long)t * NS + s) * NI + d4) = out;
}

// ---------------------------------------------------------------------------
// MFMA GRU, LDS-resident h-weights. 256 blocks (128 groups x 2 dirs),
// 832 threads = 13 waves. Wave w owns triple w = gates [16w,16w+16) r,z,n.
// Bh (21 frags/triple, fp8) bulk-copied to LDS once; x-part B (6 frags)
// in 12 VGPRs. K-loop: zero global loads for B. A: x from global (L1),
// h in LDS fp8 double-buffer. One barrier/step. h stores plain (L2-merged),
// layout [t][s][NHP] bf16.
// ---------------------------------------------------------------------------
__global__ __launch_bounds__(832, 4)
void gru_kernel(const uchar_t* __restrict__ x, const uchar_t* __restrict__ Wpk,
                const float* __restrict__ bihF, const float* __restrict__ bhhF,
                const float* __restrict__ bihB, const float* __restrict__ bhhB,
                ushort_t* __restrict__ hfo, ushort_t* __restrict__ hbo) {
    extern __shared__ __align__(16) uchar_t smem[];
    uchar_t* Bh = smem;                       // [13][7][3][512] fp8 B-frags
    uchar_t* AhB = smem + WPK_H_BYTES;        // [2][7][32][40] fp8 A(h) dbuf

    const int dir = blockIdx.x >> 7;
    const int s0 = (blockIdx.x & 127) * NPB;
    const int tid = threadIdx.x;
    const int wv = tid >> 6, ln = tid & 63;
    const int c = ln & 15, quad = ln >> 4;
    const int jl = 16 * wv + c;
    const bool jv = jl < NH;

    const float* bih = dir ? bihB : bihF;
    const float* bhh = dir ? bhhB : bhhF;
    const uchar_t* wdir = Wpk + (long)dir * WPK_DIR_BYTES;
    ushort_t* hd = dir ? hbo : hfo;

    const float br  = jv ? bih[jl] + bhh[jl] : 0.0f;
    const float bz  = jv ? bih[NH + jl] + bhh[NH + jl] : 0.0f;
    const float bnx = jv ? bih[2 * NH + jl] : 0.0f;
    const float bnh = jv ? bhh[2 * NH + jl] : 0.0f;

    // x-part B fragments in registers: i = kt2*3 + seg
    long Bx[6];
    {
        const uchar_t* wx = wdir + WPK_H_BYTES + wv * 3072 + ln * 8;
        #pragma unroll
        for (int i = 0; i < 6; i++) Bx[i] = *(const long*)(wx + i * FRAG);
    }

    // bulk-copy h-part B into LDS (16-B chunks, coalesced)
    {
        const v4u* src = (const v4u*)wdir;
        v4u* dst = (v4u*)Bh;
        for (int i = tid; i < WPK_H_BYTES / 16; i += 832) dst[i] = src[i];
    }
    // zero Ah (h0 = 0; padding stays zero forever)
    for (int i = tid; i < 2 * 7 * 32 * 40 / 4; i += 832) ((unsigned*)AhB)[i] = 0u;
    __syncthreads();

    float hold[2][4] = {};   // [mt][reg]

    for (int t = 0; t < NT; t++) {
        const int cur = t & 1, nxt = cur ^ 1;
        const int tt = dir ? (NT - 1 - t) : t;

        // x A-fragments straight from global (k-map: k = quad*8 + j)
        const uchar_t* xp = x + ((long)tt * NS + s0) * NI;
        long ax00 = ld_long_a4(xp + c * NI + quad * 8);
        long ax01 = ld_long_a4(xp + c * NI + 32 + quad * 8);
        long ax10 = ld_long_a4(xp + (16 + c) * NI + quad * 8);
        long ax11 = ld_long_a4(xp + (16 + c) * NI + 32 + quad * 8);

        f32x4 aR[2], aZ[2], aNX[2], aNH[2];
        const f32x4 vz = {0.0f, 0.0f, 0.0f, 0.0f};
        aR[0] = aR[1] = aZ[0] = aZ[1] = vz;
        aNX[0] = aNX[1] = aNH[0] = aNH[1] = vz;

        // x contribution (kt 0,1) — B from registers
        aR[0]  = __builtin_amdgcn_mfma_f32_16x16x32_fp8_fp8(ax00, Bx[0], aR[0], 0, 0, 0);
        aR[1]  = __builtin_amdgcn_mfma_f32_16x16x32_fp8_fp8(ax10, Bx[0], aR[1], 0, 0, 0);
        aZ[0]  = __builtin_amdgcn_mfma_f32_16x16x32_fp8_fp8(ax00, Bx[1], aZ[0], 0, 0, 0);
        aZ[1]  = __builtin_amdgcn_mfma_f32_16x16x32_fp8_fp8(ax10, Bx[1], aZ[1], 0, 0, 0);
        aNX[0] = __builtin_amdgcn_mfma_f32_16x16x32_fp8_fp8(ax00, Bx[2], aNX[0], 0, 0, 0);
        aNX[1] = __builtin_amdgcn_mfma_f32_16x16x32_fp8_fp8(ax10, Bx[2], aNX[1], 0, 0, 0);
        aR[0]  = __builtin_amdgcn_mfma_f32_16x16x32_fp8_fp8(ax01, Bx[3], aR[0], 0, 0, 0);
        aR[1]  = __builtin_amdgcn_mfma_f32_16x16x32_fp8_fp8(ax11, Bx[3], aR[1], 0, 0, 0);
        aZ[0]  = __builtin_amdgcn_mfma_f32_16x16x32_fp8_fp8(ax01, Bx[4], aZ[0], 0, 0, 0);
        aZ[1]  = __builtin_amdgcn_mfma_f32_16x16x32_fp8_fp8(ax11, Bx[4], aZ[1], 0, 0, 0);
        aNX[0] = __builtin_amdgcn_mfma_f32_16x16x32_fp8_fp8(ax01, Bx[5], aNX[0], 0, 0, 0);
        aNX[1] = __builtin_amdgcn_mfma_f32_16x16x32_fp8_fp8(ax11, Bx[5], aNX[1], 0, 0, 0);

        // h contribution (kt 0..6) — B from LDS (own triple), A from LDS
        const uchar_t* bt = Bh + wv * (21 * FRAG) + ln * 8;
        const uchar_t* ac = AhB + (long)cur * 8960;
        #pragma unroll
        for (int kt = 0; kt < 7; kt++) {
            long ah0 = *(const long*)(ac + (kt * 32 + c) * 40 + quad * 8);
            long ah1 = *(const long*)(ac + (kt * 32 + 16 + c) * 40 + quad * 8);
            long bR = *(const long*)(bt + (kt * 3 + 0) * FRAG);
            long bZ = *(const long*)(bt + (kt * 3 + 1) * FRAG);
            long bN = *(const long*)(bt + (kt * 3 + 2) * FRAG);
            aR[0]  = __builtin_amdgcn_mfma_f32_16x16x32_fp8_fp8(ah0, bR, aR[0], 0, 0, 0);
            aR[1]  = __builtin_amdgcn_mfma_f32_16x16x32_fp8_fp8(ah1, bR, aR[1], 0, 0, 0);
            aZ[0]  = __builtin_amdgcn_mfma_f32_16x16x32_fp8_fp8(ah0, bZ, aZ[0], 0, 0, 0);
            aZ[1]  = __builtin_amdgcn_mfma_f32_16x16x32_fp8_fp8(ah1, bZ, aZ[1], 0, 0, 0);
            aNH[0] = __builtin_amdgcn_mfma_f32_16x16x32_fp8_fp8(ah0, bN, aNH[0], 0, 0, 0);
            aNH[1] = __builtin_amdgcn_mfma_f32_16x16x32_fp8_fp8(ah1, bN, aNH[1], 0, 0, 0);
        }

        // activations + h update; C/D layout: row = quad*4+reg, col = c
        ushort_t* hdt = hd + (long)tt * NS * NHP;
        uchar_t* an = AhB + (long)nxt * 8960;
        #pragma unroll
        for (int mt = 0; mt < 2; mt++) {
            #pragma unroll
            for (int reg = 0; reg < 4; reg++) {
                int mr = mt * 16 + quad * 4 + reg;
                float r = sigf(aR[mt][reg] + br);
                float z = sigf(aZ[mt][reg] + bz);
                float n = tanh_fast(aNX[mt][reg] + bnx + r * (aNH[mt][reg] + bnh));
                float hn = (1.0f - z) * n + z * hold[mt][reg];
                hold[mt][reg] = hn;
                if (mr < NPB && jv) {
                    an[((jl >> 5) * 32 + mr) * 40 + (jl & 31)] = f2fp8(hn);
                    hdt[(s0 + mr) * NHP + jl] = f2b(hn);
                }
            }
        }
        __syncthreads();
    }
}

// ---------------------------------------------------------------------------
// Word-level attention: one block per sentence. h layout is [t][s][NHP] bf16.
// ---------------------------------------------------------------------------
__global__ __launch_bounds__(256)
void attn_kernel(const ushort_t* __restrict__ hf, const ushort_t* __restrict__ hb,
                 const float* __restrict__ aw, float* __restrict__ H) {
    int s = blockIdx.x;
    int tid = threadIdx.x;
    __shared__ __align__(16) float tup[NT][NH];
    __shared__ float sc[NT];
    __shared__ float inv_s;
    // stage hf+hb (8-B vector loads; NHP rows are 8B-aligned)
    for (int i = tid; i < NT * NH / 4; i += 256) {
        int t = i / 50, j4 = (i - t * 50) * 4;
        long off = ((long)t * NS + s) * NHP + j4;
        v2i uf = *(const v2i*)(hf + off);
        v2i ub = *(const v2i*)(hb + off);
        unsigned f0 = (unsigned)uf.x, f1 = (unsigned)uf.y;
        unsigned b0 = (unsigned)ub.x, b1 = (unsigned)ub.y;
        tup[t][j4]     = b2f((ushort_t)(f0 & 0xffff)) + b2f((ushort_t)(b0 & 0xffff));
        tup[t][j4 + 1] = b2f((ushort_t)(f0 >> 16))    + b2f((ushort_t)(b0 >> 16));
        tup[t][j4 + 2] = b2f((ushort_t)(f1 & 0xffff)) + b2f((ushort_t)(b1 & 0xffff));
        tup[t][j4 + 3] = b2f((ushort_t)(f1 >> 16))    + b2f((ushort_t)(b1 >> 16));
    }
    __syncthreads();
    int wvv = tid >> 6, lnn = tid & 63;
    for (int t = wvv; t < NT; t += 4) {
        float p = 0.0f;
        for (int j = lnn; j < NH; j += 64) p += tanh_fast(tup[t][j]) * aw[j];
        #pragma unroll
        for (int off = 32; off > 0; off >>= 1) p += __shfl_down(p, off, 64);
        if (lnn == 0) sc[t] = p;
    }
    __syncthreads();
    // wave-parallel softmax over T=70 (wave 0)
    if (tid < 64) {
        float v0 = sc[tid];
        float v1 = (tid + 64 < NT) ? sc[tid + 64] : -1e30f;
        float mx = fmaxf(v0, v1);
        #pragma unroll
        for (int off = 32; off > 0; off >>= 1) mx = fmaxf(mx, __shfl_xor(mx, off, 64));
        float e0 = __expf(v0 - mx);
        float e1 = (tid + 64 < NT) ? __expf(v1 - mx) : 0.0f;
        float ssum = e0 + e1;
        #pragma unroll
        for (int off = 32; off > 0; off >>= 1) ssum += __shfl_xor(ssum, off, 64);
        sc[tid] = e0;
        if (tid + 64 < NT) sc[tid + 64] = e1;
        if (tid == 0) inv_s = 1.0f / ssum;
    }
    __syncthreads();
    float inv = inv_s;
    for (int j = tid; j < NH; j += 256) {
        float acc = 0.0f;
        #pragma unroll 7
        for (int t = 0; t < NT; t++) acc += sc[t] * tup[t][j];
        H[s * NH + j] = acc * inv;
    }
}

// ---------------------------------------------------------------------------
// Bag attention + logits + BCE loss.
// ---------------------------------------------------------------------------
__global__ __launch_bounds__(256)
void bag_kernel(const float* __restrict__ H, const int* __restrict__ label,
                const float* __restrict__ sen_a, const float* __restrict__ sen_r,
                const float* __restrict__ rel, const float* __restrict__ sen_d,
                float* __restrict__ out) {
    int b = blockIdx.x;
    int tid = threadIdx.x;
    __shared__ __align__(16) float Hs[NPB][NH];
    __shared__ float e[NPB];
    __shared__ float Sv[NH];
    __shared__ float part[4];
    const float* Hb = H + b * NPB * NH;
    for (int i = tid; i < NPB * NH; i += 256) (&Hs[0][0])[i] = Hb[i];
    __syncthreads();
    int wvv = tid >> 6, lnn = tid & 63;
    for (int n = wvv; n < NPB; n += 4) {
        float p = 0.0f;
        for (int j = lnn; j < NH; j += 64) p += Hs[n][j] * sen_a[j] * sen_r[j];
        #pragma unroll
        for (int off = 32; off > 0; off >>= 1) p += __shfl_down(p, off, 64);
        if (lnn == 0) e[n] = p;
    }
    __syncthreads();
    if (tid == 0) {
        float mx = e[0];
        for (int n = 1; n < NPB; n++) mx = fmaxf(mx, e[n]);
        float sum = 0.0f;
        for (int n = 0; n < NPB; n++) { float v = __expf(e[n] - mx); e[n] = v; sum += v; }
        float inv = 1.0f / sum;
        for (int n = 0; n < NPB; n++) e[n] *= inv;
    }
    __syncthreads();
    for (int j = tid; j < NH; j += 256) {
        float acc = 0.0f;
        #pragma unroll
        for (int n = 0; n < NPB; n++) acc += e[n] * Hs[n][j];
        Sv[j] = acc;
    }
    __syncthreads();
    float bce = 0.0f;
    if (tid < NREL) {
        float acc = 0.0f;
        #pragma unroll 4
        for (int j = 0; j < NH; j++) acc += Sv[j] * rel[tid * NH + j];
        float l = acc + sen_d[tid];
        out[1 + b * NREL + tid] = l;
        float tgt = (label[b] == tid) ? 1.0f : 0.0f;
        bce = fmaxf(l, 0.0f) - l * tgt + log1pf(__expf(-fabsf(l)));
    }
    #pragma unroll
    for (int off = 32; off > 0; off >>= 1) bce += __shfl_down(bce, off, 64);
    if (lnn == 0) part[wvv] = bce;
    __syncthreads();
    if (tid == 0) {
        float tot = (part[0] + part[1] + part[2] + part[3]) * (1.0f / NREL);
        atomicAdd(out, tot);
    }
}

// ---------------------------------------------------------------------------
extern "C" void kernel_launch(void* const* d_in, const int* in_sizes, int n_in,
                              void* d_out, int out_size, void* d_ws, size_t ws_size,
                              hipStream_t stream) {
    const int*   tok   = (const int*)d_in[0];
    const int*   p1    = (const int*)d_in[1];
    const int*   p2    = (const int*)d_in[2];
    const int*   label = (const int*)d_in[3];
    const float* emb   = (const float*)d_in[4];
    const float* pemb  = (const float*)d_in[5];
    const float* WihF  = (const float*)d_in[6];
    const float* WhhF  = (const float*)d_in[7];
    const float* bihF  = (const float*)d_in[8];
    const float* bhhF  = (const float*)d_in[9];
    const float* WihB  = (const float*)d_in[10];
    const float* WhhB  = (const float*)d_in[11];
    const float* bihB  = (const float*)d_in[12];
    const float* bhhB  = (const float*)d_in[13];
    const float* aw    = (const float*)d_in[14];
    const float* sen_a = (const float*)d_in[15];
    const float* sen_r = (const float*)d_in[16];
    const float* rel   = (const float*)d_in[17];
    const float* sen_d = (const float*)d_in[18];

    // workspace layout (all 16B-aligned chunks)
    const long wpk_bytes = 2L * WPK_DIR_BYTES;                 // 359,424
    const long x_bytes   = (long)NT * NS * NI + 1088;          // fp8 + OOB slack
    uchar_t* Wpk  = (uchar_t*)d_ws;
    uchar_t* xbuf = Wpk + wpk_bytes;
    float*   Hbuf = (float*)(xbuf + ((x_bytes + 15) & ~15L));  // 2560*200 f32
    ushort_t* hfb = (ushort_t*)(Hbuf + NS * NH);               // [t][s][NHP] bf16
    ushort_t* hbb = hfb + (long)NT * NS * NHP;

    static bool attr_set = false;
    hipFuncSetAttribute((const void*)gru_kernel,
                        hipFuncAttributeMaxDynamicSharedMemorySize, GRU_LDS_BYTES);
    (void)attr_set;

    prep_wpk_kernel<<<(int)((wpk_bytes + 255) / 256), 256, 0, stream>>>(WihF, WhhF, WihB, WhhB, Wpk);
    gather_kernel<<<(NT * NS * 15 + 255) / 256, 256, 0, stream>>>(tok, p1, p2, emb, pemb, xbuf);
    gru_kernel<<<256, 832, GRU_LDS_BYTES, stream>>>(xbuf, Wpk, bihF, bhhF, bihB, bhhB, hfb, hbb);
    attn_kernel<<<NS, 256, 0, stream>>>(hfb, hbb, aw, Hbuf);
    hipMemsetAsync(d_out, 0, sizeof(float), stream);
    bag_kernel<<<NBAG, 256, 0, stream>>>(Hbuf, label, sen_a, sen_r, rel, sen_d, (float*)d_out);
}